// Round 6
// baseline (1410.783 us; speedup 1.0000x reference)
//
#include <hip/hip_runtime.h>
#include <cstddef>
#include <cstdint>

#define TT   32
#define NN   256
#define NLL  16
#define HH   256
#define CONDD 64
#define NEE  8
#define H3   768
#define OW   308

typedef __attribute__((ext_vector_type(8))) short bf16x8;
typedef __attribute__((ext_vector_type(4))) float f32x4;
typedef unsigned short u16;

__device__ __forceinline__ float sigm(float x)     { return 1.f / (1.f + __expf(-x)); }
__device__ __forceinline__ float tanhfast(float x) { return 1.f - 2.f / (__expf(2.f * x) + 1.f); }
__device__ __forceinline__ float bf2f(u16 h) {
    union { unsigned u; float f; } v; v.u = ((unsigned)h) << 16; return v.f;
}
__device__ __forceinline__ u16 f2bf(float f) {   // round-to-nearest-even
    union { float f; unsigned u; } v; v.f = f;
    unsigned r = v.u + 0x7fffu + ((v.u >> 16) & 1u);
    return (u16)(r >> 16);
}
__device__ __forceinline__ bf16x8 pack8(float4 f0, float4 f1) {
    union { u16 u[8]; bf16x8 v; } r;
    r.u[0] = f2bf(f0.x); r.u[1] = f2bf(f0.y); r.u[2] = f2bf(f0.z); r.u[3] = f2bf(f0.w);
    r.u[4] = f2bf(f1.x); r.u[5] = f2bf(f1.y); r.u[6] = f2bf(f1.z); r.u[7] = f2bf(f1.w);
    return r.v;
}
#define MFMA(a, b, c) __builtin_amdgcn_mfma_f32_16x16x32_bf16(a, b, c, 0, 0, 0)

// ---- async global->LDS staging (T3/T4) --------------------------------------
__device__ __forceinline__ void gl_lds16(const u16* g, u16* l) {
    __builtin_amdgcn_global_load_lds(
        (const __attribute__((address_space(1))) unsigned int*)(const void*)g,
        (__attribute__((address_space(3))) unsigned int*)(void*)l, 16, 0, 0);
}
// Stage one 96-col chunk (48KB) of a [768][256] bf16 matrix into LDS.
// Linear LDS dest; SOURCE granule pre-swizzled (gs ^ (row&7)) so the swizzled
// ds_read_b128 on the consumer side hits the b128 bank floor (involution).
__device__ __forceinline__ void stage96(const u16* __restrict__ W, u16* buf,
                                        int c, int w, int lane) {
#pragma unroll
    for (int r = 0; r < 6; ++r) {
        int gran = (w * 6 + r) * 64 + lane;       // 0..3071
        int row  = gran >> 5, gs = gran & 31;
        const u16* src = W + ((size_t)(c * 96 + row) << 8) + ((gs ^ (row & 7)) << 3);
        gl_lds16(src, buf + ((w * 6 + r) << 9));  // wave-uniform LDS base
    }
}
__device__ __forceinline__ void wait_vm6()   { asm volatile("s_waitcnt vmcnt(6)" ::: "memory"); }
__device__ __forceinline__ void wait_vm0()   { asm volatile("s_waitcnt vmcnt(0)" ::: "memory"); }
__device__ __forceinline__ void wait_lgkm0() { asm volatile("s_waitcnt lgkmcnt(0)" ::: "memory"); }
__device__ __forceinline__ void bar() {
    asm volatile("" ::: "memory");
    __builtin_amdgcn_s_barrier();
    asm volatile("" ::: "memory");
}

// ---------------------------------------------------------------------------
// Merged fp32 -> bf16 weight casts
// ---------------------------------------------------------------------------
__global__ __launch_bounds__(256) void k_prep(
    const float* __restrict__ gwhh_f, const float* __restrict__ gwhh_b,
    const float* __restrict__ cwhh,  const float* __restrict__ mw1,
    const float* __restrict__ mw2,   const float* __restrict__ w2,
    const float* __restrict__ cwih,
    u16* __restrict__ whhbf_f, u16* __restrict__ whhbf_b, u16* __restrict__ cwhhbf,
    u16* __restrict__ mw1bf, u16* __restrict__ mw2bf, u16* __restrict__ w2bf,
    u16* __restrict__ cwcbf)
{
    long i = (long)blockIdx.x * 256 + threadIdx.x;
    if (i < 196608) { whhbf_f[i] = f2bf(gwhh_f[i]); return; } i -= 196608;
    if (i < 196608) { whhbf_b[i] = f2bf(gwhh_b[i]); return; } i -= 196608;
    if (i < 196608) { cwhhbf[i]  = f2bf(cwhh[i]);  return; } i -= 196608;
    if (i < 65536)  { mw1bf[i]   = f2bf(mw1[i]);   return; } i -= 65536;
    if (i < 65536)  { mw2bf[i]   = f2bf(mw2[i]);   return; } i -= 65536;
    if (i < 4096)   { long r = i >> 8, c = i & 255;
                      w2bf[i] = (r < 8) ? f2bf(w2[r * 256 + c]) : (u16)0; return; } i -= 4096;
    if (i < 49152)  { long r = i >> 6, c = i & 63; cwcbf[i] = f2bf(cwih[r * 320 + c]); }
}

// ---------------------------------------------------------------------------
// Per-token gi tables via MFMA: 3 mats x 6 col-chunks of 128.
// gif/gib: E @ gwih^T + gbih + gbhh(r,z rows only).
// gic:     E @ cwih[:,64:]^T + cbih + cbhh(r,z rows only).
// ---------------------------------------------------------------------------
__global__ __launch_bounds__(256) void k_tok(
    const float* __restrict__ embed,
    const float* __restrict__ gwih_f, const float* __restrict__ gbih_f, const float* __restrict__ gbhh_f,
    const float* __restrict__ gwih_b, const float* __restrict__ gbih_b, const float* __restrict__ gbhh_b,
    const float* __restrict__ cwih,   const float* __restrict__ cbih,   const float* __restrict__ cbhh,
    u16* __restrict__ gif, u16* __restrict__ gib, u16* __restrict__ gic)
{
    const int mat = blockIdx.x / 6, ch = blockIdx.x % 6;
    const int tid = threadIdx.x, lane = tid & 63, w = tid >> 6;   // wave = m-tile
    const int lm = lane & 15, lg = lane >> 4;
    const float *W, *b1, *b2v; int wstride, woff; u16* dst;
    if (mat == 0)      { W = gwih_f; b1 = gbih_f; b2v = gbhh_f; wstride = 256; woff = 0;  dst = gif; }
    else if (mat == 1) { W = gwih_b; b1 = gbih_b; b2v = gbhh_b; wstride = 256; woff = 0;  dst = gib; }
    else               { W = cwih;   b1 = cbih;   b2v = cbhh;   wstride = 320; woff = 64; dst = gic; }

    bf16x8 a[8];
    #pragma unroll
    for (int ks = 0; ks < 8; ++ks) {
        const float* ep = embed + (size_t)(w * 16 + lm) * 256 + ks * 32 + lg * 8;
        a[ks] = pack8(*(const float4*)ep, *(const float4*)(ep + 4));
    }
    f32x4 acc[8];
    #pragma unroll
    for (int nt = 0; nt < 8; ++nt)
        #pragma unroll
        for (int z = 0; z < 4; ++z) acc[nt][z] = 0.f;

    #pragma unroll
    for (int nt = 0; nt < 8; ++nt) {
        int col = ch * 128 + nt * 16 + lm;
        const float* wp = W + (size_t)col * wstride + woff;
        #pragma unroll
        for (int ks = 0; ks < 8; ++ks) {
            bf16x8 b = pack8(*(const float4*)(wp + ks * 32 + lg * 8),
                             *(const float4*)(wp + ks * 32 + lg * 8 + 4));
            acc[nt] = MFMA(a[ks], b, acc[nt]);
        }
    }
    #pragma unroll
    for (int nt = 0; nt < 8; ++nt) {
        int col = ch * 128 + nt * 16 + lm;
        float bias = b1[col] + (col < 512 ? b2v[col] : 0.f);
        #pragma unroll
        for (int j = 0; j < 4; ++j) {
            int v = w * 16 + lg * 4 + j;
            dst[(size_t)v * H3 + col] = f2bf(acc[nt][j] + bias);
        }
    }
}

// ---------------------------------------------------------------------------
// w-trajectory + out[.,.,0..2] + tok_used
// ---------------------------------------------------------------------------
__global__ void k_wtraj(const int* __restrict__ actions, const int* __restrict__ w0,
                        const int* __restrict__ lines,
                        float* __restrict__ out, int* __restrict__ w_used,
                        int* __restrict__ tok_used)
{
    int n = threadIdx.x;
    int w = w0[n];
    for (int t = 0; t < TT; ++t) {
        int A = actions[((size_t)t * NN + n) * 2 + 0];
        int W = actions[((size_t)t * NN + n) * 2 + 1];
        w_used[t * NN + n] = w;
        tok_used[t * NN + n] = lines[n * NLL + w];
        int wn = w + W - NLL;
        wn = wn < 0 ? 0 : (wn > NLL - 1 ? NLL - 1 : wn);
        float* o = out + ((size_t)t * NN + n) * OW;
        o[0] = (float)A; o[1] = (float)W; o[2] = (float)wn;
        w = wn;
    }
}

// ---------------------------------------------------------------------------
// gi_full[t*256+n][col] = bf16( cond[t,n] @ cwc^T[col]  +  gic[tok_used[t,n]][col] )
// (gic already carries cbih + cbhh(r,z)).  M=8192 rows, 32 rows/block.
// ---------------------------------------------------------------------------
__global__ __launch_bounds__(256) void k_cg(
    const float* __restrict__ condition, const u16* __restrict__ cwcbf,
    const u16* __restrict__ gic, const int* __restrict__ tok_used,
    u16* __restrict__ gi_full)
{
    const int r0 = blockIdx.x * 32;
    const int tid = threadIdx.x, lane = tid & 63, w = tid >> 6;
    const int wm = w >> 1, wn = w & 1;   // 2M x 2N
    const int lm = lane & 15, lg = lane >> 4;

    bf16x8 a[2];
    #pragma unroll
    for (int ks = 0; ks < 2; ++ks) {
        const float* cp = condition + (size_t)(r0 + wm * 16 + lm) * 64 + ks * 32 + lg * 8;
        a[ks] = pack8(*(const float4*)cp, *(const float4*)(cp + 4));
    }
    f32x4 acc[24];
    #pragma unroll
    for (int jj = 0; jj < 24; ++jj)
        #pragma unroll
        for (int z = 0; z < 4; ++z) acc[jj][z] = 0.f;

    #pragma unroll
    for (int jj = 0; jj < 24; ++jj) {
        int tile = 2 * jj + wn;
        const u16* bp = cwcbf + (size_t)(tile * 16 + lm) * 64;
        #pragma unroll
        for (int ks = 0; ks < 2; ++ks)
            acc[jj] = MFMA(a[ks], *(const bf16x8*)(bp + ks * 32 + lg * 8), acc[jj]);
    }
    int wv[4];
    #pragma unroll
    for (int j = 0; j < 4; ++j) wv[j] = tok_used[r0 + wm * 16 + lg * 4 + j];
    #pragma unroll
    for (int jj = 0; jj < 24; ++jj) {
        int col = (2 * jj + wn) * 16 + lm;
        #pragma unroll
        for (int j = 0; j < 4; ++j) {
            int g = r0 + wm * 16 + lg * 4 + j;
            float v = acc[jj][j] + bf2f(gic[(size_t)wv[j] * H3 + col]);
            gi_full[(size_t)g * H3 + col] = f2bf(v);
        }
    }
}

// ---------------------------------------------------------------------------
// MEGA: 132 blocks x 512 thr, 64 rows/block, M=64 GEMM per step.
//   bid<128: GRU (16 steps, dir/ii/nb partition, fused B-proj via MFMA)
//   bid>=128: controller (32 steps, gi_full table, writes out + Hallbf)
// Pipeline: 8 chunks x 96 cols, dbuf global_load_lds, counted vmcnt(6),
// raw barriers. Waves 4M x 2N; wave wn owns n-tiles t%2==wn; acc[3c+p]=jr map:
// acc[jr]=r-gate col (2jr+wn)*16+lm, acc[8+jr]=z, acc[16+jr]=n.
// ---------------------------------------------------------------------------
__global__ __launch_bounds__(512) void k_mega(
    const u16* __restrict__ whhbf_f, const u16* __restrict__ whhbf_b,
    const u16* __restrict__ cwhhbf,
    const u16* __restrict__ gif, const u16* __restrict__ gib,
    const float* __restrict__ gbhh_f, const float* __restrict__ gbhh_b,
    const float* __restrict__ cbhh,
    const u16* __restrict__ w2bf, const float* __restrict__ b2,
    float* __restrict__ Bf, float* __restrict__ Bb,
    const int* __restrict__ lines,
    const u16* __restrict__ gi_full, const float* __restrict__ h0,
    u16* __restrict__ Hallbf, float* __restrict__ out)
{
    __shared__ __align__(16) u16 hlds[64 * 264];      // 33.8 KB
    __shared__ __align__(16) u16 wbuf[2][96 * 256];   // 96 KB
    __shared__ __align__(16) u16 w2l[4096];           // 8 KB
    __shared__ int lns[1024];                         // 4 KB

    const int tid = threadIdx.x, lane = tid & 63, w = tid >> 6;
    const int lm = lane & 15, lg = lane >> 4;
    const int wm = w >> 1, wn = w & 1;
    const int bid = blockIdx.x;
    const bool isctrl = (bid >= 128);

    // role-dependent bindings
    int dir = 0, ii = 0, nb = 0, cb = 0;
    const u16* W; const u16* git = nullptr; const float* bnsrc;
    float* Bout = nullptr;
    if (isctrl) {
        cb = bid - 128;                       // rows cb*64..+64
        W = cwhhbf; bnsrc = cbhh;
    } else {
        dir = bid >> 6; int lb = bid & 63;
        ii = lb >> 2; nb = (lb & 3) << 6;     // 64 rows: nb..nb+63 within batch, group ii
        W    = dir ? whhbf_b : whhbf_f;
        git  = dir ? gib : gif;
        bnsrc = dir ? gbhh_b : gbhh_f;
        Bout = dir ? Bb : Bf;
    }
    const int smax = isctrl ? TT : 16;

    // per-thread constants
    float bn[8];
    #pragma unroll
    for (int jr = 0; jr < 8; ++jr) bn[jr] = bnsrc[512 + (2 * jr + wn) * 16 + lm];
    const float b2e = (lm < 8) ? b2[lm] : 0.f;

    // init LDS h + hreg
    float hreg[32];
    if (isctrl) {
        #pragma unroll
        for (int jr = 0; jr < 8; ++jr) {
            int col = (2 * jr + wn) * 16 + lm;
            #pragma unroll
            for (int j = 0; j < 4; ++j) {
                int lrow = wm * 16 + lg * 4 + j;
                float hv = h0[(size_t)(cb * 64 + lrow) * HH + col];
                hreg[jr * 4 + j] = hv;
                hlds[lrow * 264 + col] = f2bf(hv);
            }
        }
    } else {
        for (int k = tid; k < 64 * 264; k += 512) hlds[k] = 0;
        #pragma unroll
        for (int k = 0; k < 32; ++k) hreg[k] = 0.f;
        for (int k = tid; k < 1024; k += 512)
            lns[k] = lines[(nb + (k >> 4)) * NLL + (k & 15)];
        for (int k = tid; k < 4096; k += 512) w2l[k] = w2bf[k];
    }
    __syncthreads();

    // initial A-fragments
    bf16x8 a[8];
    #pragma unroll
    for (int ks = 0; ks < 8; ++ks)
        a[ks] = *(const bf16x8*)&hlds[(wm * 16 + lm) * 264 + ks * 32 + lg * 8];

    stage96(W, wbuf[0], 0, w, lane);   // prologue chunk 0

    for (int s = 0; s < smax; ++s) {
        f32x4 acc[24];
        #pragma unroll
        for (int jj = 0; jj < 24; ++jj)
            #pragma unroll
            for (int z = 0; z < 4; ++z) acc[jj][z] = 0.f;

        #pragma unroll
        for (int c = 0; c < 8; ++c) {
            if (c == 7 && s == smax - 1) { wait_vm0(); }
            else { stage96(W, wbuf[(c + 1) & 1], (c + 1) & 7, w, lane); wait_vm6(); }
            bar();
            const u16* wb = wbuf[c & 1];
            #pragma unroll
            for (int p = 0; p < 3; ++p) {
                const int lt = wn + 2 * p;
                const u16* bp = wb + ((lt * 16 + lm) << 8);
                #pragma unroll
                for (int ks = 0; ks < 8; ++ks) {
                    bf16x8 b = *(const bf16x8*)(bp + (((ks * 4 + lg) ^ (lm & 7)) << 3));
                    acc[c * 3 + p] = MFMA(a[ks], b, acc[c * 3 + p]);
                }
            }
            bar();
        }

        // ---- gate phase ----
        if (isctrl) {
            #pragma unroll
            for (int jr = 0; jr < 8; ++jr) {
                const int col = (2 * jr + wn) * 16 + lm;
                #pragma unroll
                for (int j = 0; j < 4; ++j) {
                    const int lrow = wm * 16 + lg * 4 + j;
                    const size_t g = (size_t)s * NN + cb * 64 + lrow;
                    const u16* gi = gi_full + g * H3;
                    float rg = sigm(bf2f(gi[col])       + acc[jr][j]);
                    float zg = sigm(bf2f(gi[col + 256]) + acc[8 + jr][j]);
                    float ng = tanhfast(bf2f(gi[col + 512]) + rg * (acc[16 + jr][j] + bn[jr]));
                    float hv = (1.f - zg) * ng + zg * hreg[jr * 4 + j];
                    hreg[jr * 4 + j] = hv;
                    hlds[lrow * 264 + col] = f2bf(hv);
                    out[g * OW + 4 + col] = hv;
                    Hallbf[g * HH + col] = f2bf(hv);
                }
            }
        } else {
            const int jpos = dir ? (15 - s) : s;
            const int jt = (ii + jpos) & 15;
            #pragma unroll
            for (int jr = 0; jr < 8; ++jr) {
                const int col = (2 * jr + wn) * 16 + lm;
                #pragma unroll
                for (int j = 0; j < 4; ++j) {
                    const int lrow = wm * 16 + lg * 4 + j;
                    const int tok = lns[lrow * 16 + jt];
                    const u16* gi = git + (size_t)tok * H3;
                    float rg = sigm(bf2f(gi[col])       + acc[jr][j]);
                    float zg = sigm(bf2f(gi[col + 256]) + acc[8 + jr][j]);
                    float ng = tanhfast(bf2f(gi[col + 512]) + rg * (acc[16 + jr][j] + bn[jr]));
                    float hv = (1.f - zg) * ng + zg * hreg[jr * 4 + j];
                    hreg[jr * 4 + j] = hv;
                    hlds[lrow * 264 + col] = f2bf(hv);
                }
            }
        }
        wait_lgkm0(); bar();           // h_new visible block-wide

        // reload A-frags (h_new) — also feeds GRU B-projection
        #pragma unroll
        for (int ks = 0; ks < 8; ++ks)
            a[ks] = *(const bf16x8*)&hlds[(wm * 16 + lm) * 264 + ks * 32 + lg * 8];

        if (!isctrl) {
            const int jpos = dir ? (15 - s) : s;
            f32x4 accB;
            #pragma unroll
            for (int z = 0; z < 4; ++z) accB[z] = 0.f;
            #pragma unroll
            for (int ks = 0; ks < 8; ++ks) {
                bf16x8 wf = *(const bf16x8*)&w2l[lm * 256 + ks * 32 + lg * 8];
                accB = MFMA(a[ks], wf, accB);
            }
            if (lm < 8) {
                #pragma unroll
                for (int j = 0; j < 4; ++j) {
                    int nn = nb + wm * 16 + lg * 4 + j;
                    Bout[(((size_t)ii * NN + nn) * NLL + jpos) * NEE + lm] = sigm(accB[j] + b2e);
                }
            }
        }
    }
}

// ---------------------------------------------------------------------------
// Stick-breaking + reversals + roll into final P layout (verified)
// ---------------------------------------------------------------------------
__global__ __launch_bounds__(256) void k_stick(
    const float* __restrict__ Bf, const float* __restrict__ Bb,
    float* __restrict__ P_final)
{
    int idx = blockIdx.x * 256 + threadIdx.x;
    if (idx >= 16 * 256 * 8) return;
    int e = idx & 7, n = (idx >> 3) & 255, i = idx >> 11;
    const float* bf = Bf + ((size_t)(i * NN + n) * NLL) * NEE + e;
    const float* bb = Bb + ((size_t)(i * NN + n) * NLL) * NEE + e;
    int i2 = (i + 15) & 15;
    float* dst = P_final + ((size_t)(i2 * NN + n) * 32) * NEE + e;
    float cum = 1.f;
    #pragma unroll
    for (int m = 0; m < 16; ++m) {
        float c0 = bf[m * NEE];
        float c1 = bb[(15 - m) * NEE];
        float v0 = c0 * cum;
        cum *= (1.f - c0);
        float v1 = (m < 15) ? c1 * cum : cum;
        cum *= (1.f - c1);
        dst[(size_t)(((17 + m) & 31)) * NEE] = v0;
        dst[(size_t)((16 - m)) * NEE]        = v1;
    }
}

// ---------------------------------------------------------------------------
// Batched MLP layer: Out = bf16(relu(A @ W^T + bias)), A (8192,256) bf16
// ---------------------------------------------------------------------------
__global__ __launch_bounds__(256) void k_mlp(
    const u16* __restrict__ A, const u16* __restrict__ W,
    const float* __restrict__ bias, u16* __restrict__ Out)
{
    __shared__ u16 ot[32 * 264];
    const int g0 = blockIdx.x * 32;
    const int tid = threadIdx.x, lane = tid & 63, w = tid >> 6;
    const int lm = lane & 15, lg = lane >> 4;
    f32x4 acc[4][2];
    #pragma unroll
    for (int c = 0; c < 4; ++c)
        #pragma unroll
        for (int r = 0; r < 2; ++r)
            #pragma unroll
            for (int z = 0; z < 4; ++z) acc[c][r][z] = 0.f;
    #pragma unroll
    for (int ks = 0; ks < 8; ++ks) {
        bf16x8 a0 = *(const bf16x8*)&A[(size_t)(g0 + lm) * 256 + ks * 32 + lg * 8];
        bf16x8 a1 = *(const bf16x8*)&A[(size_t)(g0 + 16 + lm) * 256 + ks * 32 + lg * 8];
        #pragma unroll
        for (int cf = 0; cf < 4; ++cf) {
            const u16* bp = W + (size_t)(w * 64 + cf * 16 + lm) * 256 + ks * 32 + lg * 8;
            bf16x8 b = *(const bf16x8*)bp;
            acc[cf][0] = MFMA(a0, b, acc[cf][0]);
            acc[cf][1] = MFMA(a1, b, acc[cf][1]);
        }
    }
    #pragma unroll
    for (int cf = 0; cf < 4; ++cf) {
        int col = w * 64 + cf * 16 + lm;
        float bs = bias[col];
        #pragma unroll
        for (int rf = 0; rf < 2; ++rf)
            #pragma unroll
            for (int j = 0; j < 4; ++j) {
                int lrow = rf * 16 + lg * 4 + j;
                ot[lrow * 264 + col] = f2bf(fmaxf(acc[cf][rf][j] + bs, 0.f));
            }
    }
    __syncthreads();
    int lrow = tid >> 3, c0 = (tid & 7) * 32;
    const uint4* src = (const uint4*)&ot[lrow * 264 + c0];
    uint4* dst = (uint4*)&Out[(size_t)(g0 + lrow) * 256 + c0];
    dst[0] = src[0]; dst[1] = src[1]; dst[2] = src[2]; dst[3] = src[3];
}

// ---------------------------------------------------------------------------
// Heads: 25 logits per row + softmaxes + v + p_probs
// ---------------------------------------------------------------------------
__global__ __launch_bounds__(256) void k_heads(
    const u16* __restrict__ zbf,
    const float* __restrict__ aw, const float* __restrict__ ab,
    const float* __restrict__ ow, const float* __restrict__ ob,
    const float* __restrict__ cw, const float* __restrict__ cb,
    const float* __restrict__ P_final, const int* __restrict__ w_used,
    float* __restrict__ out)
{
    __shared__ float zt[32 * 258];
    __shared__ float hd[32][28];
    __shared__ float o8[32][8];
    __shared__ int   wv[32];
    const int g0 = blockIdx.x * 32, tid = threadIdx.x;
    {
        int lrow = tid >> 3, c0 = (tid & 7) * 32;
        const u16* src = &zbf[(size_t)(g0 + lrow) * 256 + c0];
        #pragma unroll
        for (int k = 0; k < 32; ++k) zt[lrow * 258 + c0 + k] = bf2f(src[k]);
    }
    if (tid < 32) wv[tid] = w_used[g0 + tid];
    __syncthreads();
    {
        int r = tid >> 3, s = tid & 7;
        const float* z = &zt[r * 258];
        float a1 = ab[s], a2 = ab[8 + s], a3 = ob[s], a4 = cb[0];
        const float* w1 = aw + s * 256;
        const float* w2_ = aw + (8 + s) * 256;
        const float* w3 = ow + s * 256;
        for (int c = 0; c < 256; ++c) {
            float zv = z[c];
            a1 += zv * w1[c]; a2 += zv * w2_[c]; a3 += zv * w3[c]; a4 += zv * cw[c];
        }
        hd[r][s] = a1; hd[r][8 + s] = a2; hd[r][16 + s] = a3;
        if (s == 0) hd[r][24] = a4;
    }
    __syncthreads();
    if (tid < 32) {
        int r = tid; int g = g0 + r;
        float* orow = out + (size_t)g * OW;
        float mx = hd[r][0];
        #pragma unroll
        for (int k = 1; k < 16; ++k) mx = fmaxf(mx, hd[r][k]);
        float ex[16], ssum = 0.f;
        #pragma unroll
        for (int k = 0; k < 16; ++k) { ex[k] = __expf(hd[r][k] - mx); ssum += ex[k]; }
        float inv = 1.f / ssum;
        #pragma unroll
        for (int k = 0; k < 16; ++k) orow[260 + k] = ex[k] * inv;
        orow[3] = hd[r][24];
        float mo = hd[r][16];
        #pragma unroll
        for (int k = 1; k < 8; ++k) mo = fmaxf(mo, hd[r][16 + k]);
        float eo[8], so = 0.f;
        #pragma unroll
        for (int k = 0; k < 8; ++k) { eo[k] = __expf(hd[r][16 + k] - mo); so += eo[k]; }
        float invo = 1.f / so;
        #pragma unroll
        for (int k = 0; k < 8; ++k) o8[r][k] = eo[k] * invo;
    }
    __syncthreads();
    {
        int r = tid >> 3, kb = tid & 7;
        int g = g0 + r, n = g & 255;
        const float* base = P_final + ((size_t)(wv[r] * NN + n) * 32) * NEE;
        float* orow = out + (size_t)g * OW + 276;
        #pragma unroll
        for (int m = 0; m < 4; ++m) {
            int k = kb + m * 8;
            const float* pe = base + k * NEE;
            float a = 0.f;
            #pragma unroll
            for (int e = 0; e < 8; ++e) a += pe[e] * o8[r][e];
            orow[k] = a;
        }
    }
}

// ---------------------------------------------------------------------------
extern "C" void kernel_launch(void* const* d_in, const int* in_sizes, int n_in,
                              void* d_out, int out_size, void* d_ws, size_t ws_size,
                              hipStream_t stream) {
    const float* condition = (const float*)d_in[0];
    const int*   lines     = (const int*)  d_in[1];
    const int*   actions   = (const int*)  d_in[2];
    const float* h0        = (const float*)d_in[3];
    const int*   w0        = (const int*)  d_in[4];
    const float* embed     = (const float*)d_in[5];
    const float* gwih_f    = (const float*)d_in[6];
    const float* gwhh_f    = (const float*)d_in[7];
    const float* gbih_f    = (const float*)d_in[8];
    const float* gbhh_f    = (const float*)d_in[9];
    const float* gwih_b    = (const float*)d_in[10];
    const float* gwhh_b    = (const float*)d_in[11];
    const float* gbih_b    = (const float*)d_in[12];
    const float* gbhh_b    = (const float*)d_in[13];
    const float* w2        = (const float*)d_in[14];
    const float* b2        = (const float*)d_in[15];
    const float* cwih      = (const float*)d_in[16];
    const float* cwhh      = (const float*)d_in[17];
    const float* cbih      = (const float*)d_in[18];
    const float* cbhh      = (const float*)d_in[19];
    const float* mw1       = (const float*)d_in[20];
    const float* mb1       = (const float*)d_in[21];
    const float* mw2       = (const float*)d_in[22];
    const float* mb2       = (const float*)d_in[23];
    const float* ow        = (const float*)d_in[24];
    const float* ob        = (const float*)d_in[25];
    const float* aw        = (const float*)d_in[26];
    const float* ab        = (const float*)d_in[27];
    const float* cw        = (const float*)d_in[28];
    const float* cb        = (const float*)d_in[29];
    float* out = (float*)d_out;

    // workspace carve-up (~23 MB, aliased)
    char* base = (char*)d_ws;
    auto alloc = [&](size_t bytes) { char* r = base; base += (bytes + 255) & ~(size_t)255; return r; };
    u16*   gif_tok = (u16*)alloc(64 * H3 * 2);
    u16*   gib_tok = (u16*)alloc(64 * H3 * 2);
    u16*   gic_tok = (u16*)alloc(64 * H3 * 2);
    u16*   whhbf_f = (u16*)alloc(H3 * 256 * 2);
    u16*   whhbf_b = (u16*)alloc(H3 * 256 * 2);
    u16*   cwhhbf  = (u16*)alloc(H3 * 256 * 2);
    u16*   mw1bf   = (u16*)alloc(256 * 256 * 2);
    u16*   mw2bf   = (u16*)alloc(256 * 256 * 2);
    u16*   w2bf    = (u16*)alloc(16 * 256 * 2);
    u16*   cwcbf   = (u16*)alloc(H3 * 64 * 2);
    u16*   gi_full = (u16*)alloc((size_t)TT * NN * H3 * 2);   // 12.6 MB
    float* Bf      = (float*)alloc((size_t)16 * 256 * 16 * 8 * 4);
    float* Bb      = (float*)alloc((size_t)16 * 256 * 16 * 8 * 4);
    u16*   Hallbf  = (u16*)alloc((size_t)TT * NN * 256 * 2);
    int*   w_used  = (int*)alloc((size_t)TT * NN * 4);
    int*   tok_used= (int*)alloc((size_t)TT * NN * 4);
    // aliases (dead-after-mega / dead-after-stick regions)
    float* P_final = (float*)gi_full;                          // 4 MB, written post-mega
    u16*   zbf     = (u16*)((char*)gi_full + (size_t)4 * 1024 * 1024);  // 4 MB
    u16*   z1bf    = (u16*)Bf;                                 // after k_stick

    k_prep<<<3024, 256, 0, stream>>>(gwhh_f, gwhh_b, cwhh, mw1, mw2, w2, cwih,
                                     whhbf_f, whhbf_b, cwhhbf, mw1bf, mw2bf, w2bf, cwcbf);

    k_tok<<<18, 256, 0, stream>>>(embed,
                                  gwih_f, gbih_f, gbhh_f,
                                  gwih_b, gbih_b, gbhh_b,
                                  cwih, cbih, cbhh,
                                  gif_tok, gib_tok, gic_tok);

    k_wtraj<<<1, 256, 0, stream>>>(actions, w0, lines, out, w_used, tok_used);

    k_cg<<<256, 256, 0, stream>>>(condition, cwcbf, gic_tok, tok_used, gi_full);

    k_mega<<<132, 512, 0, stream>>>(whhbf_f, whhbf_b, cwhhbf,
                                    gif_tok, gib_tok, gbhh_f, gbhh_b, cbhh,
                                    w2bf, b2, Bf, Bb, lines,
                                    gi_full, h0, Hallbf, out);

    k_stick<<<128, 256, 0, stream>>>(Bf, Bb, P_final);

    k_mlp<<<256, 256, 0, stream>>>(Hallbf, mw1bf, mb1, z1bf);
    k_mlp<<<256, 256, 0, stream>>>(z1bf, mw2bf, mb2, zbf);

    k_heads<<<256, 256, 0, stream>>>(zbf, aw, ab, ow, ob, cw, cb, P_final, w_used, out);
}